// Round 6
// baseline (367.730 us; speedup 1.0000x reference)
//
#include <hip/hip_runtime.h>
#include <hip/hip_bf16.h>
#include <stdint.h>
#include <stddef.h>

typedef __attribute__((ext_vector_type(4))) float f32x4;
typedef __attribute__((ext_vector_type(8))) short s16x8;

#define B_    8
#define L_    8192
#define N_    256
#define DOUT_ 256
#define M_    8192      // complex FFT length = n_fft/2
#define GSTRIDE 8200    // complex row stride for U/G (8193 used)

__device__ __forceinline__ unsigned short f2bf(float f) {
  unsigned int x = __float_as_uint(f);
  x += 0x7fff + ((x >> 16) & 1);   // RNE
  return (unsigned short)(x >> 16);
}

__device__ __forceinline__ float2 cmul(float2 a, float2 b) {
  return make_float2(a.x * b.x - a.y * b.y, a.x * b.y + a.y * b.x);
}
// LDS index swizzle: breaks bitrev-gather 32-way bank conflicts; bijective
__device__ __forceinline__ int phi(int i) { return i ^ ((i >> 8) & 7); }
__device__ __forceinline__ int rev13(int i) { return (int)(__brev((unsigned)i) >> 19); }

// ---- kernel 1: twiddle LUT tw[k] = e^{-2*pi*i*k/16384}, k=0..8191 ----
__global__ void k_tw(float2* __restrict__ tw) {
  int k = blockIdx.x * 256 + threadIdx.x;   // 8192 threads
  float a = (float)k * 3.8349519697141029e-4f;   // 2*pi/16384
  tw[k] = make_float2(__cosf(a), -__sinf(a));
}

// ---- kernel 2: gT[o][i] = sum_n W[o][n]*h[i][n], bf16 MFMA (proven path) ----
__global__ void k_gt(const float* __restrict__ W, const float* __restrict__ h,
                     unsigned short* __restrict__ gT) {
  int gid  = blockIdx.x * 256 + threadIdx.x;
  int lane = gid & 63;
  int wid  = gid >> 6;
  int o_t  = wid >> 7;
  int i_t  = wid & 127;
  int o0 = o_t * 16, i0 = i_t * 64;
  int ln = lane & 15, hi = lane >> 4;
  f32x4 acc[4] = {};
#pragma unroll
  for (int k0 = 0; k0 < N_; k0 += 32) {
    const float* wp = W + (o0 + ln) * N_ + k0 + 8 * hi;
    float4 w0 = *(const float4*)wp;
    float4 w1 = *(const float4*)(wp + 4);
    s16x8 a;
    a[0] = (short)f2bf(w0.x); a[1] = (short)f2bf(w0.y);
    a[2] = (short)f2bf(w0.z); a[3] = (short)f2bf(w0.w);
    a[4] = (short)f2bf(w1.x); a[5] = (short)f2bf(w1.y);
    a[6] = (short)f2bf(w1.z); a[7] = (short)f2bf(w1.w);
#pragma unroll
    for (int ns = 0; ns < 4; ++ns) {
      const float* hp = h + (size_t)(i0 + 16 * ns + ln) * N_ + k0 + 8 * hi;
      float4 h0 = *(const float4*)hp;
      float4 h1 = *(const float4*)(hp + 4);
      s16x8 bb;
      bb[0] = (short)f2bf(h0.x); bb[1] = (short)f2bf(h0.y);
      bb[2] = (short)f2bf(h0.z); bb[3] = (short)f2bf(h0.w);
      bb[4] = (short)f2bf(h1.x); bb[5] = (short)f2bf(h1.y);
      bb[6] = (short)f2bf(h1.z); bb[7] = (short)f2bf(h1.w);
      acc[ns] = __builtin_amdgcn_mfma_f32_16x16x32_bf16(a, bb, acc[ns], 0, 0, 0);
    }
  }
#pragma unroll
  for (int ns = 0; ns < 4; ++ns)
#pragma unroll
    for (int q = 0; q < 4; ++q)
      gT[(size_t)(o0 + 4 * hi + q) * L_ + i0 + 16 * ns + ln] = f2bf(acc[ns][q]);
}

// ---- shared: 13 radix-2 DIF stages, in-place on swizzled LDS, natural in -> bitrev out ----
// inv=false: twiddle e^{-}, forward cfft. inv=true: conj twiddles (icfft*M, bitrev order).
__device__ __forceinline__ void fft13(float2* zc, const float2* __restrict__ tw,
                                      int tid, bool inv) {
  for (int s = 0; s < 13; ++s) {
    const int sh = 12 - s;              // half = 1<<sh
    const int half = 1 << sh;
#pragma unroll
    for (int kp = 0; kp < 8; ++kp) {
      int j = tid + 512 * kp;           // 4096 butterflies
      int g = j >> sh;
      int p = j & (half - 1);
      int i0 = (g << (sh + 1)) + p;
      int i1 = i0 + half;
      int a0 = phi(i0), a1 = phi(i1);
      float2 a = zc[a0];
      float2 b = zc[a1];
      float2 w = tw[p << (s + 1)];
      if (inv) w.y = -w.y;
      zc[a0] = make_float2(a.x + b.x, a.y + b.y);
      float2 d = make_float2(a.x - b.x, a.y - b.y);
      zc[a1] = cmul(d, w);
    }
    __syncthreads();
  }
}

// ---- kernel 3: forward rffts. wg<8: U_b = rfft(pad(u[b])); wg>=8: G_o = rfft(pad(g[:,o])) ----
__global__ __launch_bounds__(512, 4) void k_ffwd(const float* __restrict__ u,
                                                 const unsigned short* __restrict__ gT,
                                                 const float2* __restrict__ tw,
                                                 float2* __restrict__ U,
                                                 float2* __restrict__ G) {
  __shared__ float2 zc[M_];   // 64 KB
  const int wg = blockIdx.x;
  const int tid = threadIdx.x;

  // load z[t] = x[2t] + i*x[2t+1]; x zero-padded past 8192 -> z[t]=0 for t>=4096
  if (wg < 8) {
    const float2* src = (const float2*)(u + wg * L_);
#pragma unroll 4
    for (int kp = 0; kp < 16; ++kp) {
      int t = tid + 512 * kp;
      zc[phi(t)] = (t < 4096) ? src[t] : make_float2(0.f, 0.f);
    }
  } else {
    const unsigned int* src = (const unsigned int*)(gT + (size_t)(wg - 8) * L_);
#pragma unroll 4
    for (int kp = 0; kp < 16; ++kp) {
      int t = tid + 512 * kp;
      float2 v = make_float2(0.f, 0.f);
      if (t < 4096) {
        unsigned int pr = src[t];   // 2 bf16
        v.x = __uint_as_float(pr << 16);
        v.y = __uint_as_float(pr & 0xffff0000u);
      }
      zc[phi(t)] = v;
    }
  }
  __syncthreads();

  fft13(zc, tw, tid, false);

  // unpack to true rfft bins X[k], k=0..8192 (gather bitrev), store natural
  float2* dst = (wg < 8) ? (U + (size_t)wg * GSTRIDE) : (G + (size_t)(wg - 8) * GSTRIDE);
#pragma unroll 4
  for (int kp = 0; kp < 16; ++kp) {
    int k = tid + 512 * kp;
    float2 zk  = zc[phi(rev13(k))];
    float2 zmk = zc[phi(rev13((M_ - k) & (M_ - 1)))];
    float2 E = make_float2(0.5f * (zk.x + zmk.x), 0.5f * (zk.y - zmk.y));
    float2 O = make_float2(0.5f * (zk.y + zmk.y), 0.5f * (zmk.x - zk.x));
    float2 w = tw[k];
    float2 X = cmul(w, O);
    dst[k] = make_float2(E.x + X.x, E.y + X.y);
  }
  if (tid == 0) {
    float2 z0 = zc[0];   // phi(0)=0, rev(0)=0
    dst[M_] = make_float2(z0.x - z0.y, 0.f);   // X[8192] = Re(Z0) - Im(Z0)
  }
}

// ---- kernel 4: per (b,o): Y = U_b * G_o ; y = irfft(Y)[0:8192] ; out[b,:,o] = y ----
__global__ __launch_bounds__(512, 4) void k_conv(const float2* __restrict__ U,
                                                 const float2* __restrict__ G,
                                                 const float2* __restrict__ tw,
                                                 float* __restrict__ out) {
  __shared__ float2 zc[M_];   // 64 KB
  const int wg = blockIdx.x;     // 2048
  const int b = wg >> 8;
  const int o = wg & 255;
  const int tid = threadIdx.x;
  const float2* Ub = U + (size_t)b * GSTRIDE;
  const float2* Go = G + (size_t)o * GSTRIDE;

  // real-pack: Z[k] = E[k] + i*O[k],  E=(Y[k]+conj(Y[M-k]))/2, O=(Y[k]-conj(Y[M-k]))/2 * e^{+i pi k/M}
#pragma unroll 4
  for (int kp = 0; kp < 16; ++kp) {
    int k = tid + 512 * kp;            // 0..8191; pair index M_-k in 1..8192 (bin 8192 valid)
    float2 Yk  = cmul(Ub[k], Go[k]);
    float2 Ymk = cmul(Ub[M_ - k], Go[M_ - k]);
    float2 E = make_float2(0.5f * (Yk.x + Ymk.x), 0.5f * (Yk.y - Ymk.y));
    float2 D = make_float2(0.5f * (Yk.x - Ymk.x), 0.5f * (Yk.y + Ymk.y));
    float2 w = tw[k];                  // e^{+i t} = conj(tw)
    float2 O = make_float2(D.x * w.x + D.y * w.y, -D.x * w.y + D.y * w.x);
    zc[phi(k)] = make_float2(E.x - O.y, E.y + O.x);
  }
  __syncthreads();

  fft13(zc, tw, tid, true);   // icfft * 8192, bitrev order

  // y[2t]=Re z[t], y[2t+1]=Im z[t]; only t<4096 needed (l<8192); gather bitrev
  const float s1 = 1.0f / 8192.0f;
  float* ob = out + (size_t)b * (L_ * DOUT_) + o;
#pragma unroll 2
  for (int kp = 0; kp < 8; ++kp) {
    int t = tid + 512 * kp;            // 0..4095
    float2 z = zc[phi(rev13(t))];
    ob[(size_t)(2 * t) * DOUT_]     = z.x * s1;
    ob[(size_t)(2 * t + 1) * DOUT_] = z.y * s1;
  }
}

extern "C" void kernel_launch(void* const* d_in, const int* in_sizes, int n_in,
                              void* d_out, int out_size, void* d_ws, size_t ws_size,
                              hipStream_t stream) {
  const float* u = (const float*)d_in[0];   // [8, 8192, 1]
  const float* h = (const float*)d_in[1];   // [8192, 256]
  const float* W = (const float*)d_in[2];   // [256, 256]
  float* out = (float*)d_out;               // [8, 8192, 256]

  char* ws = (char*)d_ws;
  unsigned short* gT = (unsigned short*)ws;                       // 4 MB bf16 [256][8192]
  float2* tw = (float2*)(ws + (size_t)4 * 1024 * 1024);           // 64 KB
  float2* U  = (float2*)(ws + (size_t)4 * 1024 * 1024 + 65536);   // 8*8200*8 = 512.5 KB
  float2* G  = (float2*)(ws + (size_t)4 * 1024 * 1024 + 65536 + 524800);  // 256*8200*8 = 16.0 MB

  k_tw<<<32, 256, 0, stream>>>(tw);
  k_gt<<<512, 256, 0, stream>>>(W, h, gT);
  k_ffwd<<<264, 512, 0, stream>>>(u, gT, tw, U, G);
  k_conv<<<2048, 512, 0, stream>>>(U, G, tw, out);
}

// Round 7
// 235.240 us; speedup vs baseline: 1.5632x; 1.5632x over previous
//
#include <hip/hip_runtime.h>
#include <hip/hip_bf16.h>
#include <stdint.h>
#include <stddef.h>

typedef __attribute__((ext_vector_type(4))) float f32x4;
typedef __attribute__((ext_vector_type(8))) short s16x8;

#define B_    8
#define L_    8192
#define N_    256
#define DOUT_ 256
#define M_    8192      // complex FFT length = n_fft/2
#define GSTRIDE 8200    // complex row stride for U/G (8193 used)

__device__ __forceinline__ unsigned short f2bf(float f) {
  unsigned int x = __float_as_uint(f);
  x += 0x7fff + ((x >> 16) & 1);   // RNE
  return (unsigned short)(x >> 16);
}

__device__ __forceinline__ float2 cmul(float2 a, float2 b) {
  return make_float2(a.x * b.x - a.y * b.y, a.x * b.y + a.y * b.x);
}
// LDS index swizzle: breaks bitrev-gather bank conflicts; bijective
__device__ __forceinline__ int phi(int i) { return i ^ ((i >> 8) & 7); }
__device__ __forceinline__ int rev13(int i) { return (int)(__brev((unsigned)i) >> 19); }

// ---- kernel 1: twiddle LUT tw[k] = e^{-2*pi*i*k/16384}, k=0..8191 ----
__global__ void k_tw(float2* __restrict__ tw) {
  int k = blockIdx.x * 256 + threadIdx.x;   // 8192 threads
  float a = (float)k * 3.8349519697141029e-4f;   // 2*pi/16384
  tw[k] = make_float2(__cosf(a), -__sinf(a));
}

// ---- kernel 2: gT[o][i] = sum_n W[o][n]*h[i][n], bf16 MFMA ----
__global__ void k_gt(const float* __restrict__ W, const float* __restrict__ h,
                     unsigned short* __restrict__ gT) {
  int gid  = blockIdx.x * 256 + threadIdx.x;
  int lane = gid & 63;
  int wid  = gid >> 6;
  int o_t  = wid >> 7;
  int i_t  = wid & 127;
  int o0 = o_t * 16, i0 = i_t * 64;
  int ln = lane & 15, hi = lane >> 4;
  f32x4 acc[4] = {};
#pragma unroll
  for (int k0 = 0; k0 < N_; k0 += 32) {
    const float* wp = W + (o0 + ln) * N_ + k0 + 8 * hi;
    float4 w0 = *(const float4*)wp;
    float4 w1 = *(const float4*)(wp + 4);
    s16x8 a;
    a[0] = (short)f2bf(w0.x); a[1] = (short)f2bf(w0.y);
    a[2] = (short)f2bf(w0.z); a[3] = (short)f2bf(w0.w);
    a[4] = (short)f2bf(w1.x); a[5] = (short)f2bf(w1.y);
    a[6] = (short)f2bf(w1.z); a[7] = (short)f2bf(w1.w);
#pragma unroll
    for (int ns = 0; ns < 4; ++ns) {
      const float* hp = h + (size_t)(i0 + 16 * ns + ln) * N_ + k0 + 8 * hi;
      float4 h0 = *(const float4*)hp;
      float4 h1 = *(const float4*)(hp + 4);
      s16x8 bb;
      bb[0] = (short)f2bf(h0.x); bb[1] = (short)f2bf(h0.y);
      bb[2] = (short)f2bf(h0.z); bb[3] = (short)f2bf(h0.w);
      bb[4] = (short)f2bf(h1.x); bb[5] = (short)f2bf(h1.y);
      bb[6] = (short)f2bf(h1.z); bb[7] = (short)f2bf(h1.w);
      acc[ns] = __builtin_amdgcn_mfma_f32_16x16x32_bf16(a, bb, acc[ns], 0, 0, 0);
    }
  }
#pragma unroll
  for (int ns = 0; ns < 4; ++ns)
#pragma unroll
    for (int q = 0; q < 4; ++q)
      gT[(size_t)(o0 + 4 * hi + q) * L_ + i0 + 16 * ns + ln] = f2bf(acc[ns][q]);
}

// ---- shared: 13 DIF stages as 6 fused radix-4 double-stages + 1 radix-2 ----
// natural in -> bitrev out. inv=false: tw e^{-}; inv=true: conj twiddles (icfft*M).
// Fusion identity: stage-s twiddle at p+half2 = w1 * tw[4096] = w1 * (-i)  (exact).
__device__ __forceinline__ void fft13(float2* zc, const float2* __restrict__ tw,
                                      int tid, bool inv) {
  for (int s = 0; s < 12; s += 2) {
    const int sh = 12 - s;              // stage-s half = 1<<sh
    const int half1 = 1 << sh;
    const int half2 = half1 >> 1;
#pragma unroll
    for (int kp = 0; kp < 4; ++kp) {
      int j = tid + 512 * kp;           // 2048 4-groups
      int g = j >> (sh - 1);
      int p = j & (half2 - 1);
      int base = (g << (sh + 1)) + p;
      int iA = phi(base), iB = phi(base + half2);
      int iC = phi(base + half1), iD = phi(base + half1 + half2);
      float2 A = zc[iA], Bv = zc[iB], C = zc[iC], D = zc[iD];
      float2 w1 = tw[p << (s + 1)];
      float2 w2 = tw[p << (s + 2)];
      if (inv) { w1.y = -w1.y; w2.y = -w2.y; }
      float2 w1b = inv ? make_float2(-w1.y, w1.x) : make_float2(w1.y, -w1.x);
      // stage s
      float2 t0 = make_float2(A.x + C.x, A.y + C.y);
      float2 t1 = cmul(make_float2(A.x - C.x, A.y - C.y), w1);
      float2 t2 = make_float2(Bv.x + D.x, Bv.y + D.y);
      float2 t3 = cmul(make_float2(Bv.x - D.x, Bv.y - D.y), w1b);
      // stage s+1 (twiddle idx = p mod half2 for both sub-blocks)
      zc[iA] = make_float2(t0.x + t2.x, t0.y + t2.y);
      zc[iB] = cmul(make_float2(t0.x - t2.x, t0.y - t2.y), w2);
      zc[iC] = make_float2(t1.x + t3.x, t1.y + t3.y);
      zc[iD] = cmul(make_float2(t1.x - t3.x, t1.y - t3.y), w2);
    }
    __syncthreads();
  }
  // final stage s=12: half=1, twiddle 1
#pragma unroll
  for (int kp = 0; kp < 8; ++kp) {
    int j = tid + 512 * kp;             // 4096 butterflies
    int i0 = phi(2 * j), i1 = phi(2 * j + 1);
    float2 a = zc[i0], b = zc[i1];
    zc[i0] = make_float2(a.x + b.x, a.y + b.y);
    zc[i1] = make_float2(a.x - b.x, a.y - b.y);
  }
  __syncthreads();
}

// ---- kernel 3: forward rffts. wg<8: U_b = rfft(pad(u[b])); wg>=8: G_o = rfft(pad(g[:,o])) ----
__global__ __launch_bounds__(512, 2) void k_ffwd(const float* __restrict__ u,
                                                 const unsigned short* __restrict__ gT,
                                                 const float2* __restrict__ tw,
                                                 float2* __restrict__ U,
                                                 float2* __restrict__ G) {
  __shared__ float2 zc[M_];   // 64 KB
  const int wg = blockIdx.x;
  const int tid = threadIdx.x;

  // load z[t] = x[2t] + i*x[2t+1]; zero-padded past 8192
  if (wg < 8) {
    const float2* src = (const float2*)(u + wg * L_);
#pragma unroll 4
    for (int kp = 0; kp < 16; ++kp) {
      int t = tid + 512 * kp;
      zc[phi(t)] = (t < 4096) ? src[t] : make_float2(0.f, 0.f);
    }
  } else {
    const unsigned int* src = (const unsigned int*)(gT + (size_t)(wg - 8) * L_);
#pragma unroll 4
    for (int kp = 0; kp < 16; ++kp) {
      int t = tid + 512 * kp;
      float2 v = make_float2(0.f, 0.f);
      if (t < 4096) {
        unsigned int pr = src[t];   // 2 bf16
        v.x = __uint_as_float(pr << 16);
        v.y = __uint_as_float(pr & 0xffff0000u);
      }
      zc[phi(t)] = v;
    }
  }
  __syncthreads();

  fft13(zc, tw, tid, false);

  // unpack to rfft bins X[k], gather bitrev, store natural (coalesced)
  float2* dst = (wg < 8) ? (U + (size_t)wg * GSTRIDE) : (G + (size_t)(wg - 8) * GSTRIDE);
#pragma unroll 4
  for (int kp = 0; kp < 16; ++kp) {
    int k = tid + 512 * kp;
    float2 zk  = zc[phi(rev13(k))];
    float2 zmk = zc[phi(rev13((M_ - k) & (M_ - 1)))];
    float2 E = make_float2(0.5f * (zk.x + zmk.x), 0.5f * (zk.y - zmk.y));
    float2 O = make_float2(0.5f * (zk.y + zmk.y), 0.5f * (zmk.x - zk.x));
    float2 w = tw[k];
    float2 X = cmul(w, O);
    dst[k] = make_float2(E.x + X.x, E.y + X.y);
  }
  if (tid == 0) {
    float2 z0 = zc[0];   // phi(0)=0, rev(0)=0
    dst[M_] = make_float2(z0.x - z0.y, 0.f);   // X[8192] = Re(Z0) - Im(Z0)
  }
}

// ---- kernel 4: per (b,o): Y = U_b * G_o ; y = irfft(Y)[0:8192] ; out[b,:,o] = y ----
// Block remap groups one batch b per XCD with consecutive o temporally adjacent,
// so strided 4B stores to the same 128B line (32 consecutive o) merge in that XCD's L2.
__global__ __launch_bounds__(512, 2) void k_conv(const float2* __restrict__ U,
                                                 const float2* __restrict__ G,
                                                 const float2* __restrict__ tw,
                                                 float* __restrict__ out) {
  __shared__ float2 zc[M_];   // 64 KB
  const int bid = blockIdx.x;    // 2048
  const int widx = (bid & 7) * 256 + (bid >> 3);   // xcd-grouped work index
  const int b = widx >> 8;       // == bid & 7 (one batch per XCD)
  const int o = widx & 255;      // ascending within XCD
  const int tid = threadIdx.x;
  const float2* Ub = U + (size_t)b * GSTRIDE;
  const float2* Go = G + (size_t)o * GSTRIDE;

  // real-pack: Z[k] = E[k] + i*O'[k]
#pragma unroll 4
  for (int kp = 0; kp < 16; ++kp) {
    int k = tid + 512 * kp;            // 0..8191; pair M_-k in 1..8192
    float2 Yk  = cmul(Ub[k], Go[k]);
    float2 Ymk = cmul(Ub[M_ - k], Go[M_ - k]);
    float2 E = make_float2(0.5f * (Yk.x + Ymk.x), 0.5f * (Yk.y - Ymk.y));
    float2 D = make_float2(0.5f * (Yk.x - Ymk.x), 0.5f * (Yk.y + Ymk.y));
    float2 w = tw[k];                  // need e^{+i}: conj(tw)
    float2 O = make_float2(D.x * w.x + D.y * w.y, -D.x * w.y + D.y * w.x);
    zc[phi(k)] = make_float2(E.x - O.y, E.y + O.x);
  }
  __syncthreads();

  fft13(zc, tw, tid, true);   // icfft * 8192, bitrev order

  // y[2t]=Re z[t], y[2t+1]=Im z[t]; gather bitrev; column store (L2-merged via remap)
  const float s1 = 1.0f / 8192.0f;
  float* ob = out + (size_t)b * (L_ * DOUT_) + o;
#pragma unroll 2
  for (int kp = 0; kp < 8; ++kp) {
    int t = tid + 512 * kp;            // 0..4095
    float2 z = zc[phi(rev13(t))];
    ob[(size_t)(2 * t) * DOUT_]     = z.x * s1;
    ob[(size_t)(2 * t + 1) * DOUT_] = z.y * s1;
  }
}

extern "C" void kernel_launch(void* const* d_in, const int* in_sizes, int n_in,
                              void* d_out, int out_size, void* d_ws, size_t ws_size,
                              hipStream_t stream) {
  const float* u = (const float*)d_in[0];   // [8, 8192, 1]
  const float* h = (const float*)d_in[1];   // [8192, 256]
  const float* W = (const float*)d_in[2];   // [256, 256]
  float* out = (float*)d_out;               // [8, 8192, 256]

  char* ws = (char*)d_ws;
  unsigned short* gT = (unsigned short*)ws;                       // 4 MB bf16 [256][8192]
  float2* tw = (float2*)(ws + (size_t)4 * 1024 * 1024);           // 64 KB
  float2* U  = (float2*)(ws + (size_t)4 * 1024 * 1024 + 65536);   // 512.5 KB
  float2* G  = (float2*)(ws + (size_t)4 * 1024 * 1024 + 65536 + 524800);  // 16.0 MB

  k_tw<<<32, 256, 0, stream>>>(tw);
  k_gt<<<512, 256, 0, stream>>>(W, h, gT);
  k_ffwd<<<264, 512, 0, stream>>>(u, gT, tw, U, G);
  k_conv<<<2048, 512, 0, stream>>>(U, G, tw, out);
}

// Round 8
// 188.452 us; speedup vs baseline: 1.9513x; 1.2483x over previous
//
#include <hip/hip_runtime.h>
#include <hip/hip_bf16.h>
#include <stdint.h>
#include <stddef.h>

typedef __attribute__((ext_vector_type(4))) float f32x4;
typedef __attribute__((ext_vector_type(8))) short s16x8;

#define B_    8
#define L_    8192
#define N_    256
#define DOUT_ 256
#define M_    8192      // complex FFT length = n_fft/2
#define GSTRIDE 8200    // complex row stride for U/G (8193 used)
#define RC    0.70710678118654752f

__device__ __forceinline__ unsigned short f2bf(float f) {
  unsigned int x = __float_as_uint(f);
  x += 0x7fff + ((x >> 16) & 1);   // RNE
  return (unsigned short)(x >> 16);
}

__device__ __forceinline__ float2 cmul(float2 a, float2 b) {
  return make_float2(a.x * b.x - a.y * b.y, a.x * b.y + a.y * b.x);
}
__device__ __forceinline__ float2 cadd(float2 a, float2 b) { return make_float2(a.x + b.x, a.y + b.y); }
__device__ __forceinline__ float2 csub(float2 a, float2 b) { return make_float2(a.x - b.x, a.y - b.y); }

// LDS index swizzle: folds bits 4-10 into bank-pair bits; <=4-way on every
// access pattern (radix passes, sequential, bitrev gather). Bijective.
__device__ __forceinline__ int phi(int i) { return i ^ (((i >> 4) ^ (i >> 7)) & 15); }
__device__ __forceinline__ int rev13(int i) { return (int)(__brev((unsigned)i) >> 19); }

// w is the FORWARD twiddle; INV applies conjugate
template<bool INV> __device__ __forceinline__ float2 twmul(float2 x, float2 w) {
  return INV ? make_float2(x.x * w.x + x.y * w.y, x.y * w.x - x.x * w.y)
             : make_float2(x.x * w.x - x.y * w.y, x.x * w.y + x.y * w.x);
}
template<bool INV> __device__ __forceinline__ float2 mul_mi(float2 x) {   // *(−i) fwd
  return INV ? make_float2(-x.y, x.x) : make_float2(x.y, -x.x);
}
template<bool INV> __device__ __forceinline__ float2 mul_w8(float2 x) {   // *e^{−iπ/4} fwd
  return INV ? make_float2(RC * (x.x - x.y), RC * (x.x + x.y))
             : make_float2(RC * (x.x + x.y), RC * (x.y - x.x));
}
template<bool INV> __device__ __forceinline__ float2 mul_w83(float2 x) {  // *e^{−3iπ/4} fwd
  return INV ? make_float2(-RC * (x.x + x.y), RC * (x.x - x.y))
             : make_float2(RC * (x.y - x.x), -RC * (x.x + x.y));
}

// ---- kernel 1: twiddle LUT tw[k] = e^{-2*pi*i*k/16384}, k=0..8191 ----
__global__ void k_tw(float2* __restrict__ tw) {
  int k = blockIdx.x * 256 + threadIdx.x;   // 8192 threads
  float a = (float)k * 3.8349519697141029e-4f;   // 2*pi/16384
  tw[k] = make_float2(__cosf(a), -__sinf(a));
}

// ---- kernel 2: gT[o][i] = sum_n W[o][n]*h[i][n], bf16 MFMA ----
__global__ void k_gt(const float* __restrict__ W, const float* __restrict__ h,
                     unsigned short* __restrict__ gT) {
  int gid  = blockIdx.x * 256 + threadIdx.x;
  int lane = gid & 63;
  int wid  = gid >> 6;
  int o_t  = wid >> 7;
  int i_t  = wid & 127;
  int o0 = o_t * 16, i0 = i_t * 64;
  int ln = lane & 15, hi = lane >> 4;
  f32x4 acc[4] = {};
#pragma unroll
  for (int k0 = 0; k0 < N_; k0 += 32) {
    const float* wp = W + (o0 + ln) * N_ + k0 + 8 * hi;
    float4 w0 = *(const float4*)wp;
    float4 w1 = *(const float4*)(wp + 4);
    s16x8 a;
    a[0] = (short)f2bf(w0.x); a[1] = (short)f2bf(w0.y);
    a[2] = (short)f2bf(w0.z); a[3] = (short)f2bf(w0.w);
    a[4] = (short)f2bf(w1.x); a[5] = (short)f2bf(w1.y);
    a[6] = (short)f2bf(w1.z); a[7] = (short)f2bf(w1.w);
#pragma unroll
    for (int ns = 0; ns < 4; ++ns) {
      const float* hp = h + (size_t)(i0 + 16 * ns + ln) * N_ + k0 + 8 * hi;
      float4 h0 = *(const float4*)hp;
      float4 h1 = *(const float4*)(hp + 4);
      s16x8 bb;
      bb[0] = (short)f2bf(h0.x); bb[1] = (short)f2bf(h0.y);
      bb[2] = (short)f2bf(h0.z); bb[3] = (short)f2bf(h0.w);
      bb[4] = (short)f2bf(h1.x); bb[5] = (short)f2bf(h1.y);
      bb[6] = (short)f2bf(h1.z); bb[7] = (short)f2bf(h1.w);
      acc[ns] = __builtin_amdgcn_mfma_f32_16x16x32_bf16(a, bb, acc[ns], 0, 0, 0);
    }
  }
#pragma unroll
  for (int ns = 0; ns < 4; ++ns)
#pragma unroll
    for (int q = 0; q < 4; ++q)
      gT[(size_t)(o0 + 4 * hi + q) * L_ + i0 + 16 * ns + ln] = f2bf(acc[ns][q]);
}

// ---- shared: 13 DIF stages = 3 fused radix-8 passes (s=0,3,6) + 1 radix-16 pass (s=9..12) ----
// natural in -> bitrev out. Twiddle factorization (exact):
//  stage s pair at p+kQ: tw[(p+kQ)*2^{s+1}] = tw[p*2^{s+1}] * w8^k  (Q*2^{s+1} = 2048)
//  stage s+1: w2 * (-i)^k ; stage s+2: w4. Radix-16 pass has p=0 -> fixed roots tw[1024k].
template<bool INV>
__device__ __forceinline__ void fft13(float2* zc, const float2* __restrict__ tw, int tid) {
#pragma unroll
  for (int s = 0; s <= 6; s += 3) {
    const int shQ = 10 - s;
    const int Q = 1 << shQ;
#pragma unroll
    for (int it = 0; it < 2; ++it) {
      int j = tid + 512 * it;
      int g = j >> shQ;
      int p = j & (Q - 1);
      int base = (g << (shQ + 3)) + p;
      int ix[8];
      float2 a[8];
#pragma unroll
      for (int k = 0; k < 8; ++k) ix[k] = phi(base + (k << shQ));
#pragma unroll
      for (int k = 0; k < 8; ++k) a[k] = zc[ix[k]];
      float2 w1 = tw[p << (s + 1)];
      float2 w2 = tw[p << (s + 2)];
      float2 w4 = tw[p << (s + 3)];
      // stage s: pairs (k, k+4), tw = w1 * w8^k
      float2 b[8];
#pragma unroll
      for (int k = 0; k < 4; ++k) {
        b[k] = cadd(a[k], a[k + 4]);
        float2 t = twmul<INV>(csub(a[k], a[k + 4]), w1);
        if (k == 1) t = mul_w8<INV>(t);
        else if (k == 2) t = mul_mi<INV>(t);
        else if (k == 3) t = mul_w83<INV>(t);
        b[k + 4] = t;
      }
      // stage s+1: pairs (k, k+2) per 4-block, tw = w2 * (-i)^k
      float2 c[8];
#pragma unroll
      for (int blk = 0; blk < 8; blk += 4)
#pragma unroll
        for (int k = 0; k < 2; ++k) {
          c[blk + k] = cadd(b[blk + k], b[blk + k + 2]);
          float2 t = twmul<INV>(csub(b[blk + k], b[blk + k + 2]), w2);
          if (k == 1) t = mul_mi<INV>(t);
          c[blk + k + 2] = t;
        }
      // stage s+2: pairs (k, k+1), tw = w4
#pragma unroll
      for (int blk = 0; blk < 8; blk += 2) {
        zc[ix[blk]]     = cadd(c[blk], c[blk + 1]);
        zc[ix[blk + 1]] = twmul<INV>(csub(c[blk], c[blk + 1]), w4);
      }
    }
    __syncthreads();
  }
  // radix-16 pass: stages 9..12 on contiguous 16-groups (p=0)
  {
    const int base = tid << 4;
    int ix[16];
    float2 a[16];
#pragma unroll
    for (int k = 0; k < 16; ++k) ix[k] = phi(base + k);
#pragma unroll
    for (int k = 0; k < 16; ++k) a[k] = zc[ix[k]];
    // stage 9: pairs (k, k+8), tw = tw[1024k] (16th roots)
    float2 b[16];
#pragma unroll
    for (int k = 0; k < 8; ++k) {
      b[k] = cadd(a[k], a[k + 8]);
      float2 t = csub(a[k], a[k + 8]);
      if (k) t = twmul<INV>(t, tw[k << 10]);
      b[k + 8] = t;
    }
    // stage 10: pairs (k, k+4) per 8-block, tw = w8^{k}
    float2 c[16];
#pragma unroll
    for (int blk = 0; blk < 16; blk += 8)
#pragma unroll
      for (int k = 0; k < 4; ++k) {
        c[blk + k] = cadd(b[blk + k], b[blk + k + 4]);
        float2 t = csub(b[blk + k], b[blk + k + 4]);
        if (k == 1) t = mul_w8<INV>(t);
        else if (k == 2) t = mul_mi<INV>(t);
        else if (k == 3) t = mul_w83<INV>(t);
        c[blk + k + 4] = t;
      }
    // stage 11: pairs (k, k+2) per 4-block, tw = (-i)^{k&1}
    float2 d[16];
#pragma unroll
    for (int blk = 0; blk < 16; blk += 4) {
      d[blk]     = cadd(c[blk], c[blk + 2]);
      d[blk + 2] = csub(c[blk], c[blk + 2]);
      d[blk + 1] = cadd(c[blk + 1], c[blk + 3]);
      d[blk + 3] = mul_mi<INV>(csub(c[blk + 1], c[blk + 3]));
    }
    // stage 12: pairs (k, k+1)
#pragma unroll
    for (int blk = 0; blk < 16; blk += 2) {
      zc[ix[blk]]     = cadd(d[blk], d[blk + 1]);
      zc[ix[blk + 1]] = csub(d[blk], d[blk + 1]);
    }
  }
  __syncthreads();
}

// ---- kernel 3: forward rffts. wg<8: U_b = rfft(pad(u[b])); wg>=8: G_o = rfft(pad(g[:,o])) ----
__global__ __launch_bounds__(512, 4) void k_ffwd(const float* __restrict__ u,
                                                 const unsigned short* __restrict__ gT,
                                                 const float2* __restrict__ tw,
                                                 float2* __restrict__ U,
                                                 float2* __restrict__ G) {
  __shared__ float2 zc[M_];   // 64 KB
  const int wg = blockIdx.x;
  const int tid = threadIdx.x;

  if (wg < 8) {
    const float2* src = (const float2*)(u + wg * L_);
#pragma unroll 4
    for (int kp = 0; kp < 16; ++kp) {
      int t = tid + 512 * kp;
      zc[phi(t)] = (t < 4096) ? src[t] : make_float2(0.f, 0.f);
    }
  } else {
    const unsigned int* src = (const unsigned int*)(gT + (size_t)(wg - 8) * L_);
#pragma unroll 4
    for (int kp = 0; kp < 16; ++kp) {
      int t = tid + 512 * kp;
      float2 v = make_float2(0.f, 0.f);
      if (t < 4096) {
        unsigned int pr = src[t];   // 2 bf16
        v.x = __uint_as_float(pr << 16);
        v.y = __uint_as_float(pr & 0xffff0000u);
      }
      zc[phi(t)] = v;
    }
  }
  __syncthreads();

  fft13<false>(zc, tw, tid);

  // unpack to rfft bins X[k], gather bitrev, store natural (coalesced)
  float2* dst = (wg < 8) ? (U + (size_t)wg * GSTRIDE) : (G + (size_t)(wg - 8) * GSTRIDE);
#pragma unroll 4
  for (int kp = 0; kp < 16; ++kp) {
    int k = tid + 512 * kp;
    float2 zk  = zc[phi(rev13(k))];
    float2 zmk = zc[phi(rev13((M_ - k) & (M_ - 1)))];
    float2 E = make_float2(0.5f * (zk.x + zmk.x), 0.5f * (zk.y - zmk.y));
    float2 O = make_float2(0.5f * (zk.y + zmk.y), 0.5f * (zmk.x - zk.x));
    float2 w = tw[k];
    float2 X = cmul(w, O);
    dst[k] = make_float2(E.x + X.x, E.y + X.y);
  }
  if (tid == 0) {
    float2 z0 = zc[0];   // phi(0)=0, rev(0)=0
    dst[M_] = make_float2(z0.x - z0.y, 0.f);   // X[8192] = Re(Z0) - Im(Z0)
  }
}

// ---- kernel 4: per (b,o): Y = U_b * G_o ; y = irfft(Y)[0:8192] ; out[b,:,o] = y ----
// Block remap: one batch per XCD, consecutive o temporally adjacent -> strided
// stores to the same 128B line merge in that XCD's L2 (R7: WRITE_SIZE 757->67MB).
__global__ __launch_bounds__(512, 4) void k_conv(const float2* __restrict__ U,
                                                 const float2* __restrict__ G,
                                                 const float2* __restrict__ tw,
                                                 float* __restrict__ out) {
  __shared__ float2 zc[M_];   // 64 KB
  const int bid = blockIdx.x;    // 2048
  const int widx = (bid & 7) * 256 + (bid >> 3);   // xcd-grouped work index
  const int b = widx >> 8;
  const int o = widx & 255;
  const int tid = threadIdx.x;
  const float2* Ub = U + (size_t)b * GSTRIDE;
  const float2* Go = G + (size_t)o * GSTRIDE;

  // real-pack: Z[k] = E[k] + i*O'[k]
#pragma unroll 4
  for (int kp = 0; kp < 16; ++kp) {
    int k = tid + 512 * kp;            // 0..8191; pair M_-k in 1..8192
    float2 Yk  = cmul(Ub[k], Go[k]);
    float2 Ymk = cmul(Ub[M_ - k], Go[M_ - k]);
    float2 E = make_float2(0.5f * (Yk.x + Ymk.x), 0.5f * (Yk.y - Ymk.y));
    float2 D = make_float2(0.5f * (Yk.x - Ymk.x), 0.5f * (Yk.y + Ymk.y));
    float2 w = tw[k];                  // need e^{+i}: conj(tw)
    float2 O = make_float2(D.x * w.x + D.y * w.y, -D.x * w.y + D.y * w.x);
    zc[phi(k)] = make_float2(E.x - O.y, E.y + O.x);
  }
  __syncthreads();

  fft13<true>(zc, tw, tid);   // icfft * 8192, bitrev order

  // y[2t]=Re z[t], y[2t+1]=Im z[t]; gather bitrev; column store (L2-merged via remap)
  const float s1 = 1.0f / 8192.0f;
  float* ob = out + (size_t)b * (L_ * DOUT_) + o;
#pragma unroll 2
  for (int kp = 0; kp < 8; ++kp) {
    int t = tid + 512 * kp;            // 0..4095
    float2 z = zc[phi(rev13(t))];
    ob[(size_t)(2 * t) * DOUT_]     = z.x * s1;
    ob[(size_t)(2 * t + 1) * DOUT_] = z.y * s1;
  }
}

extern "C" void kernel_launch(void* const* d_in, const int* in_sizes, int n_in,
                              void* d_out, int out_size, void* d_ws, size_t ws_size,
                              hipStream_t stream) {
  const float* u = (const float*)d_in[0];   // [8, 8192, 1]
  const float* h = (const float*)d_in[1];   // [8192, 256]
  const float* W = (const float*)d_in[2];   // [256, 256]
  float* out = (float*)d_out;               // [8, 8192, 256]

  char* ws = (char*)d_ws;
  unsigned short* gT = (unsigned short*)ws;                       // 4 MB bf16 [256][8192]
  float2* tw = (float2*)(ws + (size_t)4 * 1024 * 1024);           // 64 KB
  float2* U  = (float2*)(ws + (size_t)4 * 1024 * 1024 + 65536);   // 512.5 KB
  float2* G  = (float2*)(ws + (size_t)4 * 1024 * 1024 + 65536 + 524800);  // 16.0 MB

  k_tw<<<32, 256, 0, stream>>>(tw);
  k_gt<<<512, 256, 0, stream>>>(W, h, gT);
  k_ffwd<<<264, 512, 0, stream>>>(u, gT, tw, U, G);
  k_conv<<<2048, 512, 0, stream>>>(U, G, tw, out);
}

// Round 10
// 187.482 us; speedup vs baseline: 1.9614x; 1.0052x over previous
//
#include <hip/hip_runtime.h>
#include <hip/hip_bf16.h>
#include <stdint.h>
#include <stddef.h>

typedef __attribute__((ext_vector_type(4))) float f32x4;
typedef __attribute__((ext_vector_type(8))) short s16x8;

#define B_    8
#define L_    8192
#define N_    256
#define DOUT_ 256
#define M_    8192      // complex FFT length = n_fft/2
#define GSTRIDE 8200    // complex row stride for U/G (8193 used)
#define RC    0.70710678118654752f
#define C8    0.92387953251128675613f   // cos(pi/8)
#define S8    0.38268343236508977173f   // sin(pi/8)

__device__ __forceinline__ unsigned short f2bf(float f) {
  unsigned int x = __float_as_uint(f);
  x += 0x7fff + ((x >> 16) & 1);   // RNE
  return (unsigned short)(x >> 16);
}

__device__ __forceinline__ float2 cmul(float2 a, float2 b) {
  return make_float2(a.x * b.x - a.y * b.y, a.x * b.y + a.y * b.x);
}
__device__ __forceinline__ float2 cadd(float2 a, float2 b) { return make_float2(a.x + b.x, a.y + b.y); }
__device__ __forceinline__ float2 csub(float2 a, float2 b) { return make_float2(a.x - b.x, a.y - b.y); }

// LDS index swizzle. BIT 0 PRESERVED (R9 bug: old phi XORed bit 0, breaking the
// fused (m, m+1) float4 pair reads: wrong partner element + misaligned b128).
// Pattern folds bits 4..12 into bits 1..3: radix passes stay <=2-way, bitrev
// gather ~4-way (i>>10 term spreads the lane-varying high bits). Bijective.
__device__ __forceinline__ int phi(int i) {
  return i ^ ((((i >> 4) ^ (i >> 7) ^ (i >> 10)) & 7) << 1);
}
__device__ __forceinline__ int rev13(int i) { return (int)(__brev((unsigned)i) >> 19); }

// w is the FORWARD twiddle; INV applies conjugate
template<bool INV> __device__ __forceinline__ float2 twmul(float2 x, float2 w) {
  return INV ? make_float2(x.x * w.x + x.y * w.y, x.y * w.x - x.x * w.y)
             : make_float2(x.x * w.x - x.y * w.y, x.x * w.y + x.y * w.x);
}
template<bool INV> __device__ __forceinline__ float2 mul_mi(float2 x) {   // *(−i) fwd
  return INV ? make_float2(-x.y, x.x) : make_float2(x.y, -x.x);
}
template<bool INV> __device__ __forceinline__ float2 mul_w8(float2 x) {   // *e^{−iπ/4} fwd
  return INV ? make_float2(RC * (x.x - x.y), RC * (x.x + x.y))
             : make_float2(RC * (x.x + x.y), RC * (x.y - x.x));
}
template<bool INV> __device__ __forceinline__ float2 mul_w83(float2 x) {  // *e^{−3iπ/4} fwd
  return INV ? make_float2(-RC * (x.x + x.y), RC * (x.x - x.y))
             : make_float2(RC * (x.y - x.x), -RC * (x.x + x.y));
}

// ---- radix-16 butterfly (4 DIF stages s..s+3) on a[16]; in-place ----
// Twiddle factorization (T*2^{s+1}=1024, exact): stage A tw = wA * e^{-i*pi*k/8};
// stage B: wB * w8^{k&3}; stage C: wC * (-i)^{k&1}; stage D: wD.
template<bool INV>
__device__ __forceinline__ void r16(float2* a, float2 wA, float2 wB, float2 wC, float2 wD) {
  float2 b[16];
#pragma unroll
  for (int k = 0; k < 8; ++k) {
    b[k] = cadd(a[k], a[k + 8]);
    float2 t = twmul<INV>(csub(a[k], a[k + 8]), wA);
    if (k == 1) t = twmul<INV>(t, make_float2(C8, -S8));
    else if (k == 2) t = mul_w8<INV>(t);
    else if (k == 3) t = twmul<INV>(t, make_float2(S8, -C8));
    else if (k == 4) t = mul_mi<INV>(t);
    else if (k == 5) t = twmul<INV>(t, make_float2(-S8, -C8));
    else if (k == 6) t = mul_w83<INV>(t);
    else if (k == 7) t = twmul<INV>(t, make_float2(-C8, -S8));
    b[k + 8] = t;
  }
  float2 c[16];
#pragma unroll
  for (int blk = 0; blk < 16; blk += 8)
#pragma unroll
    for (int k = 0; k < 4; ++k) {
      c[blk + k] = cadd(b[blk + k], b[blk + k + 4]);
      float2 t = twmul<INV>(csub(b[blk + k], b[blk + k + 4]), wB);
      if (k == 1) t = mul_w8<INV>(t);
      else if (k == 2) t = mul_mi<INV>(t);
      else if (k == 3) t = mul_w83<INV>(t);
      c[blk + k + 4] = t;
    }
  float2 d[16];
#pragma unroll
  for (int blk = 0; blk < 16; blk += 4)
#pragma unroll
    for (int k = 0; k < 2; ++k) {
      d[blk + k] = cadd(c[blk + k], c[blk + k + 2]);
      float2 t = twmul<INV>(csub(c[blk + k], c[blk + k + 2]), wC);
      if (k == 1) t = mul_mi<INV>(t);
      d[blk + k + 2] = t;
    }
#pragma unroll
  for (int blk = 0; blk < 16; blk += 2) {
    a[blk]     = cadd(d[blk], d[blk + 1]);
    a[blk + 1] = twmul<INV>(csub(d[blk], d[blk + 1]), wD);
  }
}

// preload the 12 per-pass base twiddles (pass i: p_i = tid & (T_i-1), T = 512,32,2)
__device__ __forceinline__ void preload_tw(const float2* __restrict__ tw, int tid, float2* twp) {
  const int p0 = tid, p1 = tid & 31, p2 = tid & 1;
  twp[0] = tw[p0 << 1];  twp[1] = tw[p0 << 2];  twp[2]  = tw[p0 << 3];  twp[3]  = tw[p0 << 4];
  twp[4] = tw[p1 << 5];  twp[5] = tw[p1 << 6];  twp[6]  = tw[p1 << 7];  twp[7]  = tw[p1 << 8];
  twp[8] = tw[p2 << 9];  twp[9] = tw[p2 << 10]; twp[10] = tw[p2 << 11]; twp[11] = tw[p2 << 12];
}

// ---- stages 0..11 = 3 radix-16 passes; stage 12 is fused into the callers ----
#define FFT_PASS(INV, SH, BASE, W0, W1, W2, W3) do { \
    const int base_ = (BASE); \
    float2 a_[16]; \
    _Pragma("unroll") \
    for (int k = 0; k < 16; ++k) a_[k] = zc[phi(base_ + (k << (SH)))]; \
    r16<INV>(a_, W0, W1, W2, W3); \
    _Pragma("unroll") \
    for (int k = 0; k < 16; ++k) zc[phi(base_ + (k << (SH)))] = a_[k]; \
  } while (0)

template<bool INV>
__device__ __forceinline__ void fft12(float2* zc, int tid, const float2* twp) {
  FFT_PASS(INV, 9, tid, twp[0], twp[1], twp[2], twp[3]);
  __syncthreads();
  FFT_PASS(INV, 5, ((tid >> 5) << 9) + (tid & 31), twp[4], twp[5], twp[6], twp[7]);
  __syncthreads();
  FFT_PASS(INV, 1, ((tid >> 1) << 5) + (tid & 1), twp[8], twp[9], twp[10], twp[11]);
  __syncthreads();
}

// ---- kernel 1: twiddle LUT tw[k] = e^{-2*pi*i*k/16384}, k=0..8191 ----
__global__ void k_tw(float2* __restrict__ tw) {
  int k = blockIdx.x * 256 + threadIdx.x;   // 8192 threads
  float a = (float)k * 3.8349519697141029e-4f;   // 2*pi/16384
  tw[k] = make_float2(__cosf(a), -__sinf(a));
}

// ---- kernel 2: gT[o][i] = sum_n W[o][n]*h[i][n], bf16 MFMA ----
__global__ void k_gt(const float* __restrict__ W, const float* __restrict__ h,
                     unsigned short* __restrict__ gT) {
  int gid  = blockIdx.x * 256 + threadIdx.x;
  int lane = gid & 63;
  int wid  = gid >> 6;
  int o_t  = wid >> 7;
  int i_t  = wid & 127;
  int o0 = o_t * 16, i0 = i_t * 64;
  int ln = lane & 15, hi = lane >> 4;
  f32x4 acc[4] = {};
#pragma unroll
  for (int k0 = 0; k0 < N_; k0 += 32) {
    const float* wp = W + (o0 + ln) * N_ + k0 + 8 * hi;
    float4 w0 = *(const float4*)wp;
    float4 w1 = *(const float4*)(wp + 4);
    s16x8 a;
    a[0] = (short)f2bf(w0.x); a[1] = (short)f2bf(w0.y);
    a[2] = (short)f2bf(w0.z); a[3] = (short)f2bf(w0.w);
    a[4] = (short)f2bf(w1.x); a[5] = (short)f2bf(w1.y);
    a[6] = (short)f2bf(w1.z); a[7] = (short)f2bf(w1.w);
#pragma unroll
    for (int ns = 0; ns < 4; ++ns) {
      const float* hp = h + (size_t)(i0 + 16 * ns + ln) * N_ + k0 + 8 * hi;
      float4 h0 = *(const float4*)hp;
      float4 h1 = *(const float4*)(hp + 4);
      s16x8 bb;
      bb[0] = (short)f2bf(h0.x); bb[1] = (short)f2bf(h0.y);
      bb[2] = (short)f2bf(h0.z); bb[3] = (short)f2bf(h0.w);
      bb[4] = (short)f2bf(h1.x); bb[5] = (short)f2bf(h1.y);
      bb[6] = (short)f2bf(h1.z); bb[7] = (short)f2bf(h1.w);
      acc[ns] = __builtin_amdgcn_mfma_f32_16x16x32_bf16(a, bb, acc[ns], 0, 0, 0);
    }
  }
#pragma unroll
  for (int ns = 0; ns < 4; ++ns)
#pragma unroll
    for (int q = 0; q < 4; ++q)
      gT[(size_t)(o0 + 4 * hi + q) * L_ + i0 + 16 * ns + ln] = f2bf(acc[ns][q]);
}

// ---- kernel 3: forward rffts. wg<8: U_b = rfft(pad(u[b])); wg>=8: G_o = rfft(pad(g[:,o])) ----
__global__ __launch_bounds__(512, 4) void k_ffwd(const float* __restrict__ u,
                                                 const unsigned short* __restrict__ gT,
                                                 const float2* __restrict__ tw,
                                                 float2* __restrict__ U,
                                                 float2* __restrict__ G) {
  __shared__ __align__(16) float2 zc[M_];   // 64 KB
  const int wg = blockIdx.x;
  const int tid = threadIdx.x;
  float2 twp[12];
  preload_tw(tw, tid, twp);

  if (wg < 8) {
    const float2* src = (const float2*)(u + wg * L_);
#pragma unroll 4
    for (int kp = 0; kp < 16; ++kp) {
      int t = tid + 512 * kp;
      zc[phi(t)] = (t < 4096) ? src[t] : make_float2(0.f, 0.f);
    }
  } else {
    const unsigned int* src = (const unsigned int*)(gT + (size_t)(wg - 8) * L_);
#pragma unroll 4
    for (int kp = 0; kp < 16; ++kp) {
      int t = tid + 512 * kp;
      float2 v = make_float2(0.f, 0.f);
      if (t < 4096) {
        unsigned int pr = src[t];   // 2 bf16
        v.x = __uint_as_float(pr << 16);
        v.y = __uint_as_float(pr & 0xffff0000u);
      }
      zc[phi(t)] = v;
    }
  }
  __syncthreads();

  fft12<false>(zc, tid, twp);

  // fused stage 12 + rfft unpack; z[m] = m even ? w[m]+w[m+1] : w[m-1]-w[m]
  // phi preserves bit 0 -> (m&~1, m|1) -> (even slot, +1): aligned, correct pair.
  float2* dst = (wg < 8) ? (U + (size_t)wg * GSTRIDE) : (G + (size_t)(wg - 8) * GSTRIDE);
#pragma unroll 4
  for (int kp = 0; kp < 16; ++kp) {
    int k = tid + 512 * kp;
    int m1 = rev13(k);
    int m2 = rev13((M_ - k) & (M_ - 1));
    float4 v1 = *(const float4*)(zc + phi(m1 & ~1));
    float4 v2 = *(const float4*)(zc + phi(m2 & ~1));
    float2 zk  = (m1 & 1) ? make_float2(v1.x - v1.z, v1.y - v1.w)
                          : make_float2(v1.x + v1.z, v1.y + v1.w);
    float2 zmk = (m2 & 1) ? make_float2(v2.x - v2.z, v2.y - v2.w)
                          : make_float2(v2.x + v2.z, v2.y + v2.w);
    float2 E = make_float2(0.5f * (zk.x + zmk.x), 0.5f * (zk.y - zmk.y));
    float2 O = make_float2(0.5f * (zk.y + zmk.y), 0.5f * (zmk.x - zk.x));
    float2 w = tw[k];
    float2 X = cmul(w, O);
    dst[k] = make_float2(E.x + X.x, E.y + X.y);
  }
  if (tid == 0) {
    float4 v = *(const float4*)zc;          // w[0], w[1]  (phi(0)=0, phi(1)=1)
    float2 z0 = make_float2(v.x + v.z, v.y + v.w);
    dst[M_] = make_float2(z0.x - z0.y, 0.f);   // X[8192] = Re(Z0) - Im(Z0)
  }
}

// ---- kernel 4: per (b,o): Y = U_b * G_o ; y = irfft(Y)[0:8192] ; out[b,:,o] = y ----
// XCD-grouped remap (R7: merges strided column stores in L2). Pack processes bin
// pairs (k, 8192-k) together: Z[M-k] = conj(E) + i*conj(O') -> half loads+flops.
__global__ __launch_bounds__(512, 4) void k_conv(const float2* __restrict__ U,
                                                 const float2* __restrict__ G,
                                                 const float2* __restrict__ tw,
                                                 float* __restrict__ out) {
  __shared__ __align__(16) float2 zc[M_];   // 64 KB
  const int bid = blockIdx.x;    // 2048
  const int widx = (bid & 7) * 256 + (bid >> 3);
  const int b = widx >> 8;
  const int o = widx & 255;
  const int tid = threadIdx.x;
  const float2* Ub = U + (size_t)b * GSTRIDE;
  const float2* Go = G + (size_t)o * GSTRIDE;
  float2 twp[12];
  preload_tw(tw, tid, twp);

#pragma unroll 2
  for (int kp = 0; kp < 8; ++kp) {
    int k = tid + 512 * kp;            // 0..4095
    float2 Yk = cmul(Ub[k], Go[k]);
    if (k == 0) {
      float2 Ym = cmul(Ub[M_], Go[M_]);
      float2 E = make_float2(0.5f * (Yk.x + Ym.x), 0.5f * (Yk.y - Ym.y));
      float2 D = make_float2(0.5f * (Yk.x - Ym.x), 0.5f * (Yk.y + Ym.y));
      zc[0] = make_float2(E.x - D.y, E.y + D.x);        // w=1 -> O'=D ; phi(0)=0
      float2 Y4 = cmul(Ub[4096], Go[4096]);
      zc[phi(4096)] = make_float2(Y4.x, -Y4.y);         // Z[4096] = conj(Y[4096])
    } else {
      float2 Ymk = cmul(Ub[M_ - k], Go[M_ - k]);
      float2 E = make_float2(0.5f * (Yk.x + Ymk.x), 0.5f * (Yk.y - Ymk.y));
      float2 D = make_float2(0.5f * (Yk.x - Ymk.x), 0.5f * (Yk.y + Ymk.y));
      float2 w = tw[k];                // O' = D * conj(tw[k]) = D * e^{+i pi k/M}
      float2 O = make_float2(D.x * w.x + D.y * w.y, -D.x * w.y + D.y * w.x);
      zc[phi(k)]      = make_float2(E.x - O.y,  E.y + O.x);
      zc[phi(M_ - k)] = make_float2(E.x + O.y, -E.y + O.x);
    }
  }
  __syncthreads();

  fft12<true>(zc, tid, twp);   // stages 0..11 of icfft (bitrev out, *8192)

  // fused stage 12: needed t<4096 <=> even bitrev index m -> only SUM outputs.
  const float s1 = 1.0f / 8192.0f;
  float* ob = out + (size_t)b * (L_ * DOUT_) + o;
#pragma unroll 2
  for (int kp = 0; kp < 8; ++kp) {
    int t = tid + 512 * kp;            // 0..4095
    int m = rev13(t);                  // even
    float4 v = *(const float4*)(zc + phi(m));   // (w[m], w[m+1]) aligned pair
    ob[(size_t)(2 * t) * DOUT_]     = (v.x + v.z) * s1;
    ob[(size_t)(2 * t + 1) * DOUT_] = (v.y + v.w) * s1;
  }
}

extern "C" void kernel_launch(void* const* d_in, const int* in_sizes, int n_in,
                              void* d_out, int out_size, void* d_ws, size_t ws_size,
                              hipStream_t stream) {
  const float* u = (const float*)d_in[0];   // [8, 8192, 1]
  const float* h = (const float*)d_in[1];   // [8192, 256]
  const float* W = (const float*)d_in[2];   // [256, 256]
  float* out = (float*)d_out;               // [8, 8192, 256]

  char* ws = (char*)d_ws;
  unsigned short* gT = (unsigned short*)ws;                       // 4 MB bf16 [256][8192]
  float2* tw = (float2*)(ws + (size_t)4 * 1024 * 1024);           // 64 KB
  float2* U  = (float2*)(ws + (size_t)4 * 1024 * 1024 + 65536);   // 512.5 KB
  float2* G  = (float2*)(ws + (size_t)4 * 1024 * 1024 + 65536 + 524800);  // 16.0 MB

  k_tw<<<32, 256, 0, stream>>>(tw);
  k_gt<<<512, 256, 0, stream>>>(W, h, gT);
  k_ffwd<<<264, 512, 0, stream>>>(u, gT, tw, U, G);
  k_conv<<<2048, 512, 0, stream>>>(U, G, tw, out);
}